// Round 1
// baseline (1830.630 us; speedup 1.0000x reference)
//
#include <hip/hip_runtime.h>
#include <math.h>

// ---------------------------------------------------------------------------
// CSR build: histogram of dst -> exclusive scan -> fill permutation
// Edge id space: [0, E) = real edges, [E, E+N) = self loops (src=dst=id-E)
// ---------------------------------------------------------------------------

__global__ void k_count(const int* __restrict__ dstArr, int* __restrict__ cnt,
                        int E, int Et) {
  int i = blockIdx.x * blockDim.x + threadIdx.x;
  if (i >= Et) return;
  int d = (i < E) ? dstArr[i] : (i - E);
  atomicAdd(&cnt[d], 1);
}

__global__ __launch_bounds__(1024) void k_scan(const int* __restrict__ cnt,
                                               int* __restrict__ row_ptr, int n) {
  __shared__ int part[1024];
  int t = threadIdx.x;
  int items = (n + 1023) / 1024;   // 49 for N=50000
  int base = t * items;
  int local[64];
  int s = 0;
  for (int j = 0; j < items; ++j) {
    int idx = base + j;
    int v = (idx < n) ? cnt[idx] : 0;
    local[j] = s;
    s += v;
  }
  part[t] = s;
  __syncthreads();
  for (int off = 1; off < 1024; off <<= 1) {
    int v = (t >= off) ? part[t - off] : 0;
    __syncthreads();
    part[t] += v;
    __syncthreads();
  }
  int excl = (t == 0) ? 0 : part[t - 1];
  for (int j = 0; j < items; ++j) {
    int idx = base + j;
    if (idx < n) row_ptr[idx] = excl + local[j];
  }
  if (t == 1023) row_ptr[n] = part[1023];
}

__global__ void k_copy(const int* __restrict__ src, int* __restrict__ dst, int n) {
  int i = blockIdx.x * blockDim.x + threadIdx.x;
  if (i < n) dst[i] = src[i];
}

__global__ void k_fill(const int* __restrict__ dstArr, int* __restrict__ cursor,
                       int* __restrict__ perm, int E, int Et) {
  int i = blockIdx.x * blockDim.x + threadIdx.x;
  if (i >= Et) return;
  int d = (i < E) ? dstArr[i] : (i - E);
  int pos = atomicAdd(&cursor[d], 1);
  perm[pos] = i;
}

// ---------------------------------------------------------------------------
// SGEMM: C[M,Nn] = A[M,K] @ B[Nn,K]^T   (both row-major, K contiguous)
// 128x128 tile, BK=8, 256 threads, 8x8 per-thread microtile.
// Nn assumed multiple of 128; M guarded.
// ---------------------------------------------------------------------------
__global__ __launch_bounds__(256) void k_sgemm_nt(
    const float* __restrict__ A, const float* __restrict__ B,
    float* __restrict__ C, int M, int Nn, int K) {
  __shared__ float As[8][132];
  __shared__ float Bs[8][132];
  int tid = threadIdx.x;
  int tx = tid & 15;    // n-group
  int ty = tid >> 4;    // m-group
  int m0 = blockIdx.y * 128;
  int n0 = blockIdx.x * 128;
  int lm = tid >> 1;            // 0..127
  int lk = (tid & 1) * 4;       // 0 or 4
  int arow = m0 + lm;
  if (arow >= M) arow = M - 1;  // clamp; rows beyond M never stored
  const float* Aptr = A + (size_t)arow * K + lk;
  const float* Bptr = B + (size_t)(n0 + lm) * K + lk;

  float acc[8][8];
#pragma unroll
  for (int i = 0; i < 8; ++i)
#pragma unroll
    for (int j = 0; j < 8; ++j) acc[i][j] = 0.f;

  for (int k0 = 0; k0 < K; k0 += 8) {
    float4 av = *(const float4*)(Aptr + k0);
    float4 bv = *(const float4*)(Bptr + k0);
    __syncthreads();
    As[lk + 0][lm] = av.x; As[lk + 1][lm] = av.y;
    As[lk + 2][lm] = av.z; As[lk + 3][lm] = av.w;
    Bs[lk + 0][lm] = bv.x; Bs[lk + 1][lm] = bv.y;
    Bs[lk + 2][lm] = bv.z; Bs[lk + 3][lm] = bv.w;
    __syncthreads();
#pragma unroll
    for (int k = 0; k < 8; ++k) {
      float ar[8], br[8];
#pragma unroll
      for (int i = 0; i < 8; ++i) ar[i] = As[k][ty * 8 + i];
#pragma unroll
      for (int j = 0; j < 8; ++j) br[j] = Bs[k][tx * 8 + j];
#pragma unroll
      for (int i = 0; i < 8; ++i)
#pragma unroll
        for (int j = 0; j < 8; ++j) acc[i][j] += ar[i] * br[j];
    }
  }
#pragma unroll
  for (int i = 0; i < 8; ++i) {
    int m = m0 + ty * 8 + i;
    if (m < M) {
      float* Cp = C + (size_t)m * Nn + n0 + tx * 8;
      *(float4*)(Cp + 0) = make_float4(acc[i][0], acc[i][1], acc[i][2], acc[i][3]);
      *(float4*)(Cp + 4) = make_float4(acc[i][4], acc[i][5], acc[i][6], acc[i][7]);
    }
  }
}

// ---------------------------------------------------------------------------
// Per-node attention scalars: s[n,h] = <h[n,h,:], a_src[h,:]>, d likewise.
// One wave per (node, head).
// ---------------------------------------------------------------------------
__global__ void k_attn_sd(const float* __restrict__ h,
                          const float* __restrict__ a_src,
                          const float* __restrict__ a_dst,
                          float* __restrict__ sArr, float* __restrict__ dArr,
                          int N, int Hh, int Cc) {
  int gid = blockIdx.x * blockDim.x + threadIdx.x;
  int wid = gid >> 6;
  int lane = gid & 63;
  if (wid >= N * Hh) return;
  int hh = wid % Hh;
  const float* row = h + (size_t)wid * Cc;  // h is [N, Hh*Cc]; wid = n*Hh+hh
  float ss = 0.f, dd = 0.f;
  for (int c = lane; c < Cc; c += 64) {
    float v = row[c];
    ss += v * a_src[hh * Cc + c];
    dd += v * a_dst[hh * Cc + c];
  }
#pragma unroll
  for (int off = 32; off; off >>= 1) {
    ss += __shfl_down(ss, off);
    dd += __shfl_down(dd, off);
  }
  if (lane == 0) { sArr[wid] = ss; dArr[wid] = dd; }
}

// ---------------------------------------------------------------------------
// Per-destination-node segment softmax + weighted aggregation (CSR, no atomics)
// out[n,c] = sum_e w_e * h[src_e, c] / (sum_e w_e + 1e-16) + bias[c]
// w_e = exp(leaky(s[src]+d[n]) - max)
// ---------------------------------------------------------------------------
template <int HH, int CT, int BLOCK, bool DOELU>
__global__ __launch_bounds__(BLOCK) void k_aggregate(
    const float* __restrict__ hin, const float* __restrict__ sArr,
    const float* __restrict__ dArr, const int* __restrict__ row_ptr,
    const int* __restrict__ perm, const int* __restrict__ srcArr,
    const float* __restrict__ bias, float* __restrict__ outp, int N, int E) {
  constexpr int CPER = CT / HH;
  constexpr int ELEMS = CT / BLOCK;
  __shared__ float mx_sh[HH];
  __shared__ float denom_sh[HH];
  __shared__ float wbuf[64 * HH];
  __shared__ int sbuf[64];

  int n = blockIdx.x;
  int t = threadIdx.x;
  int e0 = row_ptr[n], e1 = row_ptr[n + 1];
  int deg = e1 - e0;  // >= 1 (self loop)

  float dloc[HH];
#pragma unroll
  for (int h = 0; h < HH; ++h) dloc[h] = dArr[n * HH + h];

  // pass 1 (wave 0): per-head max of leaky-relu'd logits
  if (t < 64) {
    float mx[HH];
#pragma unroll
    for (int h = 0; h < HH; ++h) mx[h] = -3.0e38f;
    for (int i = t; i < deg; i += 64) {
      int eid = perm[e0 + i];
      int s = (eid < E) ? srcArr[eid] : (eid - E);
#pragma unroll
      for (int h = 0; h < HH; ++h) {
        float e = sArr[s * HH + h] + dloc[h];
        e = (e > 0.f) ? e : 0.2f * e;
        mx[h] = fmaxf(mx[h], e);
      }
    }
#pragma unroll
    for (int h = 0; h < HH; ++h) {
#pragma unroll
      for (int off = 32; off; off >>= 1) mx[h] = fmaxf(mx[h], __shfl_down(mx[h], off));
    }
    if (t == 0) {
#pragma unroll
      for (int h = 0; h < HH; ++h) { mx_sh[h] = mx[h]; denom_sh[h] = 0.f; }
    }
  }
  __syncthreads();

  float acc[ELEMS];
#pragma unroll
  for (int j = 0; j < ELEMS; ++j) acc[j] = 0.f;

  for (int base = 0; base < deg; base += 64) {
    int cn = min(64, deg - base);
    if (t < cn) {
      int eid = perm[e0 + base + t];
      int s = (eid < E) ? srcArr[eid] : (eid - E);
      sbuf[t] = s;
#pragma unroll
      for (int h = 0; h < HH; ++h) {
        float e = sArr[s * HH + h] + dloc[h];
        e = (e > 0.f) ? e : 0.2f * e;
        wbuf[t * HH + h] = __expf(e - mx_sh[h]);
      }
    }
    __syncthreads();
    if (t < HH) {
      float dsum = 0.f;
      for (int i = 0; i < cn; ++i) dsum += wbuf[i * HH + t];
      denom_sh[t] += dsum;  // single writer per h
    }
    for (int i = 0; i < cn; ++i) {
      int s = sbuf[i];
      const float* hr = hin + (size_t)s * CT;
#pragma unroll
      for (int j = 0; j < ELEMS; ++j) {
        int c = t + j * BLOCK;
        acc[j] += wbuf[i * HH + (c / CPER)] * hr[c];
      }
    }
    __syncthreads();
  }

#pragma unroll
  for (int j = 0; j < ELEMS; ++j) {
    int c = t + j * BLOCK;
    int hh = c / CPER;
    float v = acc[j] / (denom_sh[hh] + 1e-16f) + bias[c];
    if (DOELU) v = (v > 0.f) ? v : expm1f(v);
    outp[(size_t)n * CT + c] = v;
  }
}

// ---------------------------------------------------------------------------
// Allocation head: z = relu(emb @ Wh1^T + bh1); score = sigmoid(z @ Wh2^T + bh2)
// One block (128 thr) per node.
// ---------------------------------------------------------------------------
__global__ __launch_bounds__(128) void k_head(
    const float* __restrict__ emb, const float* __restrict__ Wh1,
    const float* __restrict__ bh1, const float* __restrict__ Wh2,
    const float* __restrict__ bh2, float* __restrict__ scores, int N) {
  __shared__ float xr[128];
  __shared__ float z[64];
  int n = blockIdx.x;
  int t = threadIdx.x;
  xr[t] = emb[(size_t)n * 128 + t];
  __syncthreads();
  if (t < 64) {
    float s = bh1[t];
#pragma unroll 4
    for (int k = 0; k < 128; ++k) s += Wh1[t * 128 + k] * xr[k];
    z[t] = (s > 0.f) ? s : 0.f;
  }
  __syncthreads();
  if (t < 64) {
    float v = z[t] * Wh2[t];
#pragma unroll
    for (int off = 32; off; off >>= 1) v += __shfl_down(v, off);
    if (t == 0) scores[n] = 1.f / (1.f + __expf(-(v + bh2[0])));
  }
}

// ---------------------------------------------------------------------------

extern "C" void kernel_launch(void* const* d_in, const int* in_sizes, int n_in,
                              void* d_out, int out_size, void* d_ws, size_t ws_size,
                              hipStream_t stream) {
  const float* x   = (const float*)d_in[0];
  const int*   ei  = (const int*)d_in[1];
  const float* W1  = (const float*)d_in[2];
  const float* as1 = (const float*)d_in[3];
  const float* ad1 = (const float*)d_in[4];
  const float* b1  = (const float*)d_in[5];
  const float* W2  = (const float*)d_in[6];
  const float* as2 = (const float*)d_in[7];
  const float* ad2 = (const float*)d_in[8];
  const float* b2  = (const float*)d_in[9];
  const float* W3  = (const float*)d_in[10];
  const float* as3 = (const float*)d_in[11];
  const float* ad3 = (const float*)d_in[12];
  const float* b3  = (const float*)d_in[13];
  const float* Wh1 = (const float*)d_in[14];
  const float* bh1 = (const float*)d_in[15];
  const float* Wh2 = (const float*)d_in[16];
  const float* bh2 = (const float*)d_in[17];
  float* out = (float*)d_out;

  const int F = 256, HC = 512, H = 4, C = 128;
  const int N = in_sizes[0] / F;     // 50000
  const int E = in_sizes[1] / 2;     // 800000
  const int Et = E + N;              // + self loops
  const int* srcArr = ei;
  const int* dstArr = ei + E;

  char* ws = (char*)d_ws;
  size_t off = 0;
  auto alloc = [&](size_t bytes) -> void* {
    void* p = ws + off;
    off += (bytes + 255) & ~(size_t)255;
    return p;
  };
  float* bufA   = (float*)alloc((size_t)N * HC * 4);  // 102.4 MB
  float* bufB   = (float*)alloc((size_t)N * HC * 4);  // 102.4 MB
  int* row_ptr  = (int*)alloc((size_t)(N + 1) * 4);
  int* cnt      = (int*)alloc((size_t)N * 4);
  int* cursor   = (int*)alloc((size_t)N * 4);
  int* perm     = (int*)alloc((size_t)Et * 4);
  float* sArr   = (float*)alloc((size_t)N * H * 4);
  float* dArr   = (float*)alloc((size_t)N * H * 4);
  (void)ws_size; (void)n_in; (void)out_size;

  // ---- CSR build (dst is identical across layers; rebuild each launch) ----
  hipMemsetAsync(cnt, 0, (size_t)N * 4, stream);
  int eb = (Et + 255) / 256;
  k_count<<<eb, 256, 0, stream>>>(dstArr, cnt, E, Et);
  k_scan<<<1, 1024, 0, stream>>>(cnt, row_ptr, N);
  k_copy<<<(N + 255) / 256, 256, 0, stream>>>(row_ptr, cursor, N);
  k_fill<<<eb, 256, 0, stream>>>(dstArr, cursor, perm, E, Et);

  // ---- layer 1: F -> H*C, elu ----
  dim3 g1(HC / 128, (N + 127) / 128);
  k_sgemm_nt<<<g1, 256, 0, stream>>>(x, W1, bufA, N, HC, F);
  int sdb = (N * H * 64 + 255) / 256;
  k_attn_sd<<<sdb, 256, 0, stream>>>(bufA, as1, ad1, sArr, dArr, N, H, C);
  k_aggregate<4, 512, 256, true><<<N, 256, 0, stream>>>(
      bufA, sArr, dArr, row_ptr, perm, srcArr, b1, bufB, N, E);

  // ---- layer 2: H*C -> H*C, elu ----
  k_sgemm_nt<<<g1, 256, 0, stream>>>(bufB, W2, bufA, N, HC, HC);
  k_attn_sd<<<sdb, 256, 0, stream>>>(bufA, as2, ad2, sArr, dArr, N, H, C);
  k_aggregate<4, 512, 256, true><<<N, 256, 0, stream>>>(
      bufA, sArr, dArr, row_ptr, perm, srcArr, b2, bufB, N, E);

  // ---- layer 3: H*C -> C, single head, no concat/elu -> embeddings ----
  dim3 g3(C / 128, (N + 127) / 128);
  k_sgemm_nt<<<g3, 256, 0, stream>>>(bufB, W3, bufA, N, C, HC);
  int sdb3 = (N * 64 + 255) / 256;
  k_attn_sd<<<sdb3, 256, 0, stream>>>(bufA, as3, ad3, sArr, dArr, N, 1, C);
  k_aggregate<1, 128, 128, false><<<N, 128, 0, stream>>>(
      bufA, sArr, dArr, row_ptr, perm, srcArr, b3, out, N, E);

  // ---- allocation head ----
  k_head<<<N, 128, 0, stream>>>(out, Wh1, bh1, Wh2, bh2, out + (size_t)N * C, N);
}

// Round 2
// 1377.178 us; speedup vs baseline: 1.3293x; 1.3293x over previous
//
#include <hip/hip_runtime.h>
#include <math.h>

typedef _Float16 f16;
typedef f16 f16x8 __attribute__((ext_vector_type(8)));
typedef float f32x4 __attribute__((ext_vector_type(4)));

// ---------------------------------------------------------------------------
// CSR build: histogram of dst -> exclusive scan -> fill permutation
// Edge id space: [0, E) = real edges, [E, E+N) = self loops (src=dst=id-E)
// ---------------------------------------------------------------------------

__global__ void k_count(const int* __restrict__ dstArr, int* __restrict__ cnt,
                        int E, int Et) {
  int i = blockIdx.x * blockDim.x + threadIdx.x;
  if (i >= Et) return;
  int d = (i < E) ? dstArr[i] : (i - E);
  atomicAdd(&cnt[d], 1);
}

__global__ __launch_bounds__(1024) void k_scan(const int* __restrict__ cnt,
                                               int* __restrict__ row_ptr, int n) {
  __shared__ int part[1024];
  int t = threadIdx.x;
  int items = (n + 1023) / 1024;   // 49 for N=50000
  int base = t * items;
  int local[64];
  int s = 0;
  for (int j = 0; j < items; ++j) {
    int idx = base + j;
    int v = (idx < n) ? cnt[idx] : 0;
    local[j] = s;
    s += v;
  }
  part[t] = s;
  __syncthreads();
  for (int off = 1; off < 1024; off <<= 1) {
    int v = (t >= off) ? part[t - off] : 0;
    __syncthreads();
    part[t] += v;
    __syncthreads();
  }
  int excl = (t == 0) ? 0 : part[t - 1];
  for (int j = 0; j < items; ++j) {
    int idx = base + j;
    if (idx < n) row_ptr[idx] = excl + local[j];
  }
  if (t == 1023) row_ptr[n] = part[1023];
}

__global__ void k_copy(const int* __restrict__ src, int* __restrict__ dst, int n) {
  int i = blockIdx.x * blockDim.x + threadIdx.x;
  if (i < n) dst[i] = src[i];
}

__global__ void k_fill(const int* __restrict__ dstArr, int* __restrict__ cursor,
                       int* __restrict__ perm, int E, int Et) {
  int i = blockIdx.x * blockDim.x + threadIdx.x;
  if (i >= Et) return;
  int d = (i < E) ? dstArr[i] : (i - E);
  int pos = atomicAdd(&cursor[d], 1);
  perm[pos] = i;
}

// ---------------------------------------------------------------------------
// fp32 -> fp16 conversion (vectorized by 4; n must be multiple of 4)
// ---------------------------------------------------------------------------
__global__ void k_f2h(const float* __restrict__ in, f16* __restrict__ out, int n4) {
  int i = blockIdx.x * blockDim.x + threadIdx.x;
  if (i >= n4) return;
  float4 v = ((const float4*)in)[i];
  f16 o0 = (f16)v.x, o1 = (f16)v.y, o2 = (f16)v.z, o3 = (f16)v.w;
  // store as one 8-byte chunk
  union { f16 h[4]; double d; } u;
  u.h[0] = o0; u.h[1] = o1; u.h[2] = o2; u.h[3] = o3;
  ((double*)out)[i] = u.d;
}

// ---------------------------------------------------------------------------
// HGEMM (fp16 MFMA, fp32 accumulate): C[M,Nn] = A[M,K] @ B[Nn,K]^T
// A,B fp16 row-major (K contiguous). 128x128 tile, BK=32, 256 thr = 4 waves,
// each wave a 64x64 quadrant = 4x4 grid of 16x16x32 MFMAs.
// Requires: Nn % 128 == 0, K % 32 == 0. M guarded.
// LDS row stride 40 fp16 (80 B) -> even 16B-group spread for ds_read_b128.
// ---------------------------------------------------------------------------
#define LDSW 40
__global__ __launch_bounds__(256) void k_hgemm_nt(
    const f16* __restrict__ A, const f16* __restrict__ B,
    float* __restrict__ C, int M, int Nn, int K) {
  __shared__ f16 As[128 * LDSW];
  __shared__ f16 Bs[128 * LDSW];
  int tid = threadIdx.x;
  int wave = tid >> 6, lane = tid & 63;
  int quad = lane >> 4, l16 = lane & 15;
  int m0 = blockIdx.y * 128, n0 = blockIdx.x * 128;
  int wm = (wave & 1) * 64, wn = (wave >> 1) * 64;

  // staging mapping: chunk l = r*256 + tid (r=0,1): row = l>>2, col = (l&3)*8
  int srow = tid >> 2;            // 0..63 (r adds 64)
  int scol = (tid & 3) * 8;       // 0,8,16,24
  int ar0 = m0 + srow;       if (ar0 >= M) ar0 = M - 1;
  int ar1 = m0 + srow + 64;  if (ar1 >= M) ar1 = M - 1;
  const f16* Ap0 = A + (size_t)ar0 * K + scol;
  const f16* Ap1 = A + (size_t)ar1 * K + scol;
  const f16* Bp0 = B + (size_t)(n0 + srow) * K + scol;
  const f16* Bp1 = B + (size_t)(n0 + srow + 64) * K + scol;
  f16* Asw0 = &As[srow * LDSW + scol];
  f16* Asw1 = &As[(srow + 64) * LDSW + scol];
  f16* Bsw0 = &Bs[srow * LDSW + scol];
  f16* Bsw1 = &Bs[(srow + 64) * LDSW + scol];

  const f16* Ard[4];
  const f16* Brd[4];
#pragma unroll
  for (int i = 0; i < 4; ++i) {
    Ard[i] = &As[(wm + i * 16 + l16) * LDSW + quad * 8];
    Brd[i] = &Bs[(wn + i * 16 + l16) * LDSW + quad * 8];
  }

  f32x4 acc[4][4];
#pragma unroll
  for (int i = 0; i < 4; ++i)
#pragma unroll
    for (int j = 0; j < 4; ++j) acc[i][j] = (f32x4)(0.f);

  for (int k0 = 0; k0 < K; k0 += 32) {
    f16x8 av0 = *(const f16x8*)(Ap0 + k0);
    f16x8 av1 = *(const f16x8*)(Ap1 + k0);
    f16x8 bv0 = *(const f16x8*)(Bp0 + k0);
    f16x8 bv1 = *(const f16x8*)(Bp1 + k0);
    __syncthreads();
    *(f16x8*)Asw0 = av0;
    *(f16x8*)Asw1 = av1;
    *(f16x8*)Bsw0 = bv0;
    *(f16x8*)Bsw1 = bv1;
    __syncthreads();
    f16x8 af[4], bf[4];
#pragma unroll
    for (int i = 0; i < 4; ++i) af[i] = *(const f16x8*)Ard[i];
#pragma unroll
    for (int j = 0; j < 4; ++j) bf[j] = *(const f16x8*)Brd[j];
#pragma unroll
    for (int i = 0; i < 4; ++i)
#pragma unroll
      for (int j = 0; j < 4; ++j)
        acc[i][j] = __builtin_amdgcn_mfma_f32_16x16x32_f16(af[i], bf[j], acc[i][j], 0, 0, 0);
  }

#pragma unroll
  for (int i = 0; i < 4; ++i) {
#pragma unroll
    for (int r = 0; r < 4; ++r) {
      int m = m0 + wm + i * 16 + quad * 4 + r;
      if (m < M) {
        float* Cp = C + (size_t)m * Nn + n0 + wn + l16;
#pragma unroll
        for (int j = 0; j < 4; ++j) Cp[j * 16] = acc[i][j][r];
      }
    }
  }
}

// ---------------------------------------------------------------------------
// Per-node attention scalars: s[n,h] = <h[n,h,:], a_src[h,:]>, d likewise.
// One wave per (node, head).
// ---------------------------------------------------------------------------
__global__ void k_attn_sd(const float* __restrict__ h,
                          const float* __restrict__ a_src,
                          const float* __restrict__ a_dst,
                          float* __restrict__ sArr, float* __restrict__ dArr,
                          int N, int Hh, int Cc) {
  int gid = blockIdx.x * blockDim.x + threadIdx.x;
  int wid = gid >> 6;
  int lane = gid & 63;
  if (wid >= N * Hh) return;
  int hh = wid % Hh;
  const float* row = h + (size_t)wid * Cc;
  float ss = 0.f, dd = 0.f;
  for (int c = lane; c < Cc; c += 64) {
    float v = row[c];
    ss += v * a_src[hh * Cc + c];
    dd += v * a_dst[hh * Cc + c];
  }
#pragma unroll
  for (int off = 32; off; off >>= 1) {
    ss += __shfl_down(ss, off);
    dd += __shfl_down(dd, off);
  }
  if (lane == 0) { sArr[wid] = ss; dArr[wid] = dd; }
}

// ---------------------------------------------------------------------------
// Per-destination-node segment softmax + weighted aggregation (CSR, no atomics)
// ---------------------------------------------------------------------------
template <int HH, int CT, int BLOCK, bool DOELU, typename OutT>
__global__ __launch_bounds__(BLOCK) void k_aggregate(
    const float* __restrict__ hin, const float* __restrict__ sArr,
    const float* __restrict__ dArr, const int* __restrict__ row_ptr,
    const int* __restrict__ perm, const int* __restrict__ srcArr,
    const float* __restrict__ bias, OutT* __restrict__ outp, int N, int E) {
  constexpr int CPER = CT / HH;
  constexpr int ELEMS = CT / BLOCK;
  __shared__ float mx_sh[HH];
  __shared__ float denom_sh[HH];
  __shared__ float wbuf[64 * HH];
  __shared__ int sbuf[64];

  int n = blockIdx.x;
  int t = threadIdx.x;
  int e0 = row_ptr[n], e1 = row_ptr[n + 1];
  int deg = e1 - e0;

  float dloc[HH];
#pragma unroll
  for (int h = 0; h < HH; ++h) dloc[h] = dArr[n * HH + h];

  if (t < 64) {
    float mx[HH];
#pragma unroll
    for (int h = 0; h < HH; ++h) mx[h] = -3.0e38f;
    for (int i = t; i < deg; i += 64) {
      int eid = perm[e0 + i];
      int s = (eid < E) ? srcArr[eid] : (eid - E);
#pragma unroll
      for (int h = 0; h < HH; ++h) {
        float e = sArr[s * HH + h] + dloc[h];
        e = (e > 0.f) ? e : 0.2f * e;
        mx[h] = fmaxf(mx[h], e);
      }
    }
#pragma unroll
    for (int h = 0; h < HH; ++h) {
#pragma unroll
      for (int off = 32; off; off >>= 1) mx[h] = fmaxf(mx[h], __shfl_down(mx[h], off));
    }
    if (t == 0) {
#pragma unroll
      for (int h = 0; h < HH; ++h) { mx_sh[h] = mx[h]; denom_sh[h] = 0.f; }
    }
  }
  __syncthreads();

  float acc[ELEMS];
#pragma unroll
  for (int j = 0; j < ELEMS; ++j) acc[j] = 0.f;

  for (int base = 0; base < deg; base += 64) {
    int cn = min(64, deg - base);
    if (t < cn) {
      int eid = perm[e0 + base + t];
      int s = (eid < E) ? srcArr[eid] : (eid - E);
      sbuf[t] = s;
#pragma unroll
      for (int h = 0; h < HH; ++h) {
        float e = sArr[s * HH + h] + dloc[h];
        e = (e > 0.f) ? e : 0.2f * e;
        wbuf[t * HH + h] = __expf(e - mx_sh[h]);
      }
    }
    __syncthreads();
    if (t < HH) {
      float dsum = 0.f;
      for (int i = 0; i < cn; ++i) dsum += wbuf[i * HH + t];
      denom_sh[t] += dsum;
    }
    for (int i = 0; i < cn; ++i) {
      int s = sbuf[i];
      const float* hr = hin + (size_t)s * CT;
#pragma unroll
      for (int j = 0; j < ELEMS; ++j) {
        int c = t + j * BLOCK;
        acc[j] += wbuf[i * HH + (c / CPER)] * hr[c];
      }
    }
    __syncthreads();
  }

#pragma unroll
  for (int j = 0; j < ELEMS; ++j) {
    int c = t + j * BLOCK;
    int hh = c / CPER;
    float v = acc[j] / (denom_sh[hh] + 1e-16f) + bias[c];
    if (DOELU) v = (v > 0.f) ? v : expm1f(v);
    outp[(size_t)n * CT + c] = (OutT)v;
  }
}

// ---------------------------------------------------------------------------
// Allocation head
// ---------------------------------------------------------------------------
__global__ __launch_bounds__(128) void k_head(
    const float* __restrict__ emb, const float* __restrict__ Wh1,
    const float* __restrict__ bh1, const float* __restrict__ Wh2,
    const float* __restrict__ bh2, float* __restrict__ scores, int N) {
  __shared__ float xr[128];
  __shared__ float z[64];
  int n = blockIdx.x;
  int t = threadIdx.x;
  xr[t] = emb[(size_t)n * 128 + t];
  __syncthreads();
  if (t < 64) {
    float s = bh1[t];
#pragma unroll 4
    for (int k = 0; k < 128; ++k) s += Wh1[t * 128 + k] * xr[k];
    z[t] = (s > 0.f) ? s : 0.f;
  }
  __syncthreads();
  if (t < 64) {
    float v = z[t] * Wh2[t];
#pragma unroll
    for (int off = 32; off; off >>= 1) v += __shfl_down(v, off);
    if (t == 0) scores[n] = 1.f / (1.f + __expf(-(v + bh2[0])));
  }
}

// ---------------------------------------------------------------------------

extern "C" void kernel_launch(void* const* d_in, const int* in_sizes, int n_in,
                              void* d_out, int out_size, void* d_ws, size_t ws_size,
                              hipStream_t stream) {
  const float* x   = (const float*)d_in[0];
  const int*   ei  = (const int*)d_in[1];
  const float* W1  = (const float*)d_in[2];
  const float* as1 = (const float*)d_in[3];
  const float* ad1 = (const float*)d_in[4];
  const float* b1  = (const float*)d_in[5];
  const float* W2  = (const float*)d_in[6];
  const float* as2 = (const float*)d_in[7];
  const float* ad2 = (const float*)d_in[8];
  const float* b2  = (const float*)d_in[9];
  const float* W3  = (const float*)d_in[10];
  const float* as3 = (const float*)d_in[11];
  const float* ad3 = (const float*)d_in[12];
  const float* b3  = (const float*)d_in[13];
  const float* Wh1 = (const float*)d_in[14];
  const float* bh1 = (const float*)d_in[15];
  const float* Wh2 = (const float*)d_in[16];
  const float* bh2 = (const float*)d_in[17];
  float* out = (float*)d_out;

  const int F = 256, HC = 512, H = 4, C = 128;
  const int N = in_sizes[0] / F;     // 50000
  const int E = in_sizes[1] / 2;     // 800000
  const int Et = E + N;
  const int* srcArr = ei;
  const int* dstArr = ei + E;

  char* ws = (char*)d_ws;
  size_t off = 0;
  auto alloc = [&](size_t bytes) -> void* {
    void* p = ws + off;
    off += (bytes + 255) & ~(size_t)255;
    return p;
  };
  float* bufA   = (float*)alloc((size_t)N * HC * 4);   // GEMM out (fp32), 102.4 MB
  f16*   hOut   = (f16*)alloc((size_t)N * HC * 2);     // aggregate out (fp16), 51.2 MB
  f16*   xh     = (f16*)alloc((size_t)N * F * 2);      // x fp16, 25.6 MB
  f16*   W1h    = (f16*)alloc((size_t)HC * F * 2);
  f16*   W2h    = (f16*)alloc((size_t)HC * HC * 2);
  f16*   W3h    = (f16*)alloc((size_t)C * HC * 2);
  int* row_ptr  = (int*)alloc((size_t)(N + 1) * 4);
  int* cnt      = (int*)alloc((size_t)N * 4);
  int* cursor   = (int*)alloc((size_t)N * 4);
  int* perm     = (int*)alloc((size_t)Et * 4);
  float* sArr   = (float*)alloc((size_t)N * H * 4);
  float* dArr   = (float*)alloc((size_t)N * H * 4);
  (void)ws_size; (void)n_in; (void)out_size;

  // ---- CSR build ----
  hipMemsetAsync(cnt, 0, (size_t)N * 4, stream);
  int eb = (Et + 255) / 256;
  k_count<<<eb, 256, 0, stream>>>(dstArr, cnt, E, Et);
  k_scan<<<1, 1024, 0, stream>>>(cnt, row_ptr, N);
  k_copy<<<(N + 255) / 256, 256, 0, stream>>>(row_ptr, cursor, N);
  k_fill<<<eb, 256, 0, stream>>>(dstArr, cursor, perm, E, Et);

  // ---- fp16 conversions (inputs + weights) ----
  auto cvt = [&](const float* src, f16* dst, size_t n) {
    int n4 = (int)(n / 4);
    k_f2h<<<(n4 + 255) / 256, 256, 0, stream>>>(src, dst, n4);
  };
  cvt(x, xh, (size_t)N * F);
  cvt(W1, W1h, (size_t)HC * F);
  cvt(W2, W2h, (size_t)HC * HC);
  cvt(W3, W3h, (size_t)C * HC);

  // ---- layer 1: F -> H*C, elu ----
  dim3 g1(HC / 128, (N + 127) / 128);
  k_hgemm_nt<<<g1, 256, 0, stream>>>(xh, W1h, bufA, N, HC, F);
  int sdb = (N * H * 64 + 255) / 256;
  k_attn_sd<<<sdb, 256, 0, stream>>>(bufA, as1, ad1, sArr, dArr, N, H, C);
  k_aggregate<4, 512, 256, true, f16><<<N, 256, 0, stream>>>(
      bufA, sArr, dArr, row_ptr, perm, srcArr, b1, hOut, N, E);

  // ---- layer 2: H*C -> H*C, elu ----
  k_hgemm_nt<<<g1, 256, 0, stream>>>(hOut, W2h, bufA, N, HC, HC);
  k_attn_sd<<<sdb, 256, 0, stream>>>(bufA, as2, ad2, sArr, dArr, N, H, C);
  k_aggregate<4, 512, 256, true, f16><<<N, 256, 0, stream>>>(
      bufA, sArr, dArr, row_ptr, perm, srcArr, b2, hOut, N, E);

  // ---- layer 3: H*C -> C, single head, no concat/elu -> embeddings ----
  dim3 g3(C / 128, (N + 127) / 128);
  k_hgemm_nt<<<g3, 256, 0, stream>>>(hOut, W3h, bufA, N, C, HC);
  int sdb3 = (N * 64 + 255) / 256;
  k_attn_sd<<<sdb3, 256, 0, stream>>>(bufA, as3, ad3, sArr, dArr, N, 1, C);
  k_aggregate<1, 128, 128, false, float><<<N, 128, 0, stream>>>(
      bufA, sArr, dArr, row_ptr, perm, srcArr, b3, out, N, E);

  // ---- allocation head ----
  k_head<<<N, 128, 0, stream>>>(out, Wh1, bh1, Wh2, bh2, out + (size_t)N * C, N);
}

// Round 3
// 1147.339 us; speedup vs baseline: 1.5955x; 1.2003x over previous
//
#include <hip/hip_runtime.h>
#include <math.h>

typedef _Float16 f16;
typedef f16 f16x2 __attribute__((ext_vector_type(2)));
typedef f16 f16x8 __attribute__((ext_vector_type(8)));
typedef float f32x4 __attribute__((ext_vector_type(4)));

// ---------------------------------------------------------------------------
// CSR build: histogram of dst -> exclusive scan -> fill permutation
// Edge id space: [0, E) = real edges, [E, E+N) = self loops (src=dst=id-E)
// ---------------------------------------------------------------------------

__global__ void k_count(const int* __restrict__ dstArr, int* __restrict__ cnt,
                        int E, int Et) {
  int i = blockIdx.x * blockDim.x + threadIdx.x;
  if (i >= Et) return;
  int d = (i < E) ? dstArr[i] : (i - E);
  atomicAdd(&cnt[d], 1);
}

__global__ __launch_bounds__(1024) void k_scan(const int* __restrict__ cnt,
                                               int* __restrict__ row_ptr, int n) {
  __shared__ int part[1024];
  int t = threadIdx.x;
  int items = (n + 1023) / 1024;
  int base = t * items;
  int local[64];
  int s = 0;
  for (int j = 0; j < items; ++j) {
    int idx = base + j;
    int v = (idx < n) ? cnt[idx] : 0;
    local[j] = s;
    s += v;
  }
  part[t] = s;
  __syncthreads();
  for (int off = 1; off < 1024; off <<= 1) {
    int v = (t >= off) ? part[t - off] : 0;
    __syncthreads();
    part[t] += v;
    __syncthreads();
  }
  int excl = (t == 0) ? 0 : part[t - 1];
  for (int j = 0; j < items; ++j) {
    int idx = base + j;
    if (idx < n) row_ptr[idx] = excl + local[j];
  }
  if (t == 1023) row_ptr[n] = part[1023];
}

__global__ void k_copy(const int* __restrict__ src, int* __restrict__ dst, int n) {
  int i = blockIdx.x * blockDim.x + threadIdx.x;
  if (i < n) dst[i] = src[i];
}

__global__ void k_fill(const int* __restrict__ dstArr, int* __restrict__ cursor,
                       int* __restrict__ perm, int E, int Et) {
  int i = blockIdx.x * blockDim.x + threadIdx.x;
  if (i >= Et) return;
  int d = (i < E) ? dstArr[i] : (i - E);
  int pos = atomicAdd(&cursor[d], 1);
  perm[pos] = i;
}

// ---------------------------------------------------------------------------
// fp32 -> fp16 conversion (vectorized by 4; n must be multiple of 4)
// ---------------------------------------------------------------------------
__global__ void k_f2h(const float* __restrict__ in, f16* __restrict__ out, int n4) {
  int i = blockIdx.x * blockDim.x + threadIdx.x;
  if (i >= n4) return;
  float4 v = ((const float4*)in)[i];
  union { f16 h[4]; double d; } u;
  u.h[0] = (f16)v.x; u.h[1] = (f16)v.y; u.h[2] = (f16)v.z; u.h[3] = (f16)v.w;
  ((double*)out)[i] = u.d;
}

// ---------------------------------------------------------------------------
// HGEMM (fp16 MFMA, fp32 accumulate): C[M,Nn] = A[M,K] @ B[Nn,K]^T
// 128x128 tile, BK=32, 256 thr = 4 waves, wave = 64x64 quadrant (4x4 MFMAs).
// Requires: Nn % 128 == 0, K % 32 == 0. M guarded. fp16 C output.
// ---------------------------------------------------------------------------
#define LDSW 40
__global__ __launch_bounds__(256) void k_hgemm_nt(
    const f16* __restrict__ A, const f16* __restrict__ B,
    f16* __restrict__ C, int M, int Nn, int K) {
  __shared__ f16 As[128 * LDSW];
  __shared__ f16 Bs[128 * LDSW];
  int tid = threadIdx.x;
  int wave = tid >> 6, lane = tid & 63;
  int quad = lane >> 4, l16 = lane & 15;
  int m0 = blockIdx.y * 128, n0 = blockIdx.x * 128;
  int wm = (wave & 1) * 64, wn = (wave >> 1) * 64;

  int srow = tid >> 2;
  int scol = (tid & 3) * 8;
  int ar0 = m0 + srow;       if (ar0 >= M) ar0 = M - 1;
  int ar1 = m0 + srow + 64;  if (ar1 >= M) ar1 = M - 1;
  const f16* Ap0 = A + (size_t)ar0 * K + scol;
  const f16* Ap1 = A + (size_t)ar1 * K + scol;
  const f16* Bp0 = B + (size_t)(n0 + srow) * K + scol;
  const f16* Bp1 = B + (size_t)(n0 + srow + 64) * K + scol;
  f16* Asw0 = &As[srow * LDSW + scol];
  f16* Asw1 = &As[(srow + 64) * LDSW + scol];
  f16* Bsw0 = &Bs[srow * LDSW + scol];
  f16* Bsw1 = &Bs[(srow + 64) * LDSW + scol];

  const f16* Ard[4];
  const f16* Brd[4];
#pragma unroll
  for (int i = 0; i < 4; ++i) {
    Ard[i] = &As[(wm + i * 16 + l16) * LDSW + quad * 8];
    Brd[i] = &Bs[(wn + i * 16 + l16) * LDSW + quad * 8];
  }

  f32x4 acc[4][4];
#pragma unroll
  for (int i = 0; i < 4; ++i)
#pragma unroll
    for (int j = 0; j < 4; ++j) acc[i][j] = (f32x4)(0.f);

  for (int k0 = 0; k0 < K; k0 += 32) {
    f16x8 av0 = *(const f16x8*)(Ap0 + k0);
    f16x8 av1 = *(const f16x8*)(Ap1 + k0);
    f16x8 bv0 = *(const f16x8*)(Bp0 + k0);
    f16x8 bv1 = *(const f16x8*)(Bp1 + k0);
    __syncthreads();
    *(f16x8*)Asw0 = av0;
    *(f16x8*)Asw1 = av1;
    *(f16x8*)Bsw0 = bv0;
    *(f16x8*)Bsw1 = bv1;
    __syncthreads();
    f16x8 af[4], bf[4];
#pragma unroll
    for (int i = 0; i < 4; ++i) af[i] = *(const f16x8*)Ard[i];
#pragma unroll
    for (int j = 0; j < 4; ++j) bf[j] = *(const f16x8*)Brd[j];
#pragma unroll
    for (int i = 0; i < 4; ++i)
#pragma unroll
      for (int j = 0; j < 4; ++j)
        acc[i][j] = __builtin_amdgcn_mfma_f32_16x16x32_f16(af[i], bf[j], acc[i][j], 0, 0, 0);
  }

#pragma unroll
  for (int i = 0; i < 4; ++i) {
#pragma unroll
    for (int r = 0; r < 4; ++r) {
      int m = m0 + wm + i * 16 + quad * 4 + r;
      if (m < M) {
        f16* Cp = C + (size_t)m * Nn + n0 + wn + l16;
#pragma unroll
        for (int j = 0; j < 4; ++j) Cp[j * 16] = (f16)acc[i][j][r];
      }
    }
  }
}

// ---------------------------------------------------------------------------
// Per-node attention scalars from fp16 h: s[n,h] = <h[n,h,:], a_src[h,:]>.
// One wave per (node, head); Cc assumed even.
// ---------------------------------------------------------------------------
__global__ void k_attn_sd(const f16* __restrict__ h,
                          const float* __restrict__ a_src,
                          const float* __restrict__ a_dst,
                          float* __restrict__ sArr, float* __restrict__ dArr,
                          int N, int Hh, int Cc) {
  int gid = blockIdx.x * blockDim.x + threadIdx.x;
  int wid = gid >> 6;
  int lane = gid & 63;
  if (wid >= N * Hh) return;
  int hh = wid % Hh;
  const f16x2* row = (const f16x2*)(h + (size_t)wid * Cc);
  float ss = 0.f, dd = 0.f;
  for (int c2 = lane; c2 < Cc / 2; c2 += 64) {
    f16x2 v = row[c2];
    float v0 = (float)v.x, v1 = (float)v.y;
    ss += v0 * a_src[hh * Cc + 2 * c2] + v1 * a_src[hh * Cc + 2 * c2 + 1];
    dd += v0 * a_dst[hh * Cc + 2 * c2] + v1 * a_dst[hh * Cc + 2 * c2 + 1];
  }
#pragma unroll
  for (int off = 32; off; off >>= 1) {
    ss += __shfl_down(ss, off);
    dd += __shfl_down(dd, off);
  }
  if (lane == 0) { sArr[wid] = ss; dArr[wid] = dd; }
}

// ---------------------------------------------------------------------------
// Per-destination segment softmax + aggregation (CSR, no atomics).
// BLOCK == CT/2; each thread owns one f16x2 of the output row.
// ---------------------------------------------------------------------------
template <int HH, int CT, int BLOCK, bool DOELU, typename OutT>
__global__ __launch_bounds__(BLOCK) void k_aggregate(
    const f16* __restrict__ hin, const float* __restrict__ sArr,
    const float* __restrict__ dArr, const int* __restrict__ row_ptr,
    const int* __restrict__ perm, const int* __restrict__ srcArr,
    const float* __restrict__ bias, OutT* __restrict__ outp, int N, int E) {
  static_assert(BLOCK == CT / 2, "one f16x2 per thread");
  constexpr int CPER2 = (CT / HH) / 2;
  __shared__ float mx_sh[HH];
  __shared__ float denom_sh[HH];
  __shared__ float wbuf[64 * HH];
  __shared__ int sbuf[64];

  int n = blockIdx.x;
  int t = threadIdx.x;
  int e0 = row_ptr[n], e1 = row_ptr[n + 1];
  int deg = e1 - e0;

  float dloc[HH];
#pragma unroll
  for (int h = 0; h < HH; ++h) dloc[h] = dArr[n * HH + h];

  if (t < 64) {
    float mx[HH];
#pragma unroll
    for (int h = 0; h < HH; ++h) mx[h] = -3.0e38f;
    for (int i = t; i < deg; i += 64) {
      int eid = perm[e0 + i];
      int s = (eid < E) ? srcArr[eid] : (eid - E);
#pragma unroll
      for (int h = 0; h < HH; ++h) {
        float e = sArr[s * HH + h] + dloc[h];
        e = (e > 0.f) ? e : 0.2f * e;
        mx[h] = fmaxf(mx[h], e);
      }
    }
#pragma unroll
    for (int h = 0; h < HH; ++h) {
#pragma unroll
      for (int off = 32; off; off >>= 1) mx[h] = fmaxf(mx[h], __shfl_down(mx[h], off));
    }
    if (t == 0) {
#pragma unroll
      for (int h = 0; h < HH; ++h) { mx_sh[h] = mx[h]; denom_sh[h] = 0.f; }
    }
  }
  __syncthreads();

  int hh = t / CPER2;
  float acc0 = 0.f, acc1 = 0.f;

  for (int base = 0; base < deg; base += 64) {
    int cn = min(64, deg - base);
    if (t < cn) {
      int eid = perm[e0 + base + t];
      int s = (eid < E) ? srcArr[eid] : (eid - E);
      sbuf[t] = s;
#pragma unroll
      for (int h = 0; h < HH; ++h) {
        float e = sArr[s * HH + h] + dloc[h];
        e = (e > 0.f) ? e : 0.2f * e;
        wbuf[t * HH + h] = __expf(e - mx_sh[h]);
      }
    }
    __syncthreads();
    if (t < HH) {
      float dsum = 0.f;
      for (int i = 0; i < cn; ++i) dsum += wbuf[i * HH + t];
      denom_sh[t] += dsum;
    }
    for (int i = 0; i < cn; ++i) {
      int s = sbuf[i];
      f16x2 v = ((const f16x2*)(hin + (size_t)s * CT))[t];
      float w = wbuf[i * HH + hh];
      acc0 += w * (float)v.x;
      acc1 += w * (float)v.y;
    }
    __syncthreads();
  }

  float dn = denom_sh[hh] + 1e-16f;
  float v0 = acc0 / dn + bias[2 * t];
  float v1 = acc1 / dn + bias[2 * t + 1];
  if (DOELU) {
    v0 = (v0 > 0.f) ? v0 : expm1f(v0);
    v1 = (v1 > 0.f) ? v1 : expm1f(v1);
  }
  if constexpr (sizeof(OutT) == 2) {
    f16x2 o; o.x = (f16)v0; o.y = (f16)v1;
    ((f16x2*)(outp + (size_t)n * CT))[t] = o;
  } else {
    float2 o = make_float2(v0, v1);
    ((float2*)(outp + (size_t)n * CT))[t] = o;
  }
}

// ---------------------------------------------------------------------------
// Allocation head
// ---------------------------------------------------------------------------
__global__ __launch_bounds__(128) void k_head(
    const float* __restrict__ emb, const float* __restrict__ Wh1,
    const float* __restrict__ bh1, const float* __restrict__ Wh2,
    const float* __restrict__ bh2, float* __restrict__ scores, int N) {
  __shared__ float xr[128];
  __shared__ float z[64];
  int n = blockIdx.x;
  int t = threadIdx.x;
  xr[t] = emb[(size_t)n * 128 + t];
  __syncthreads();
  if (t < 64) {
    float s = bh1[t];
#pragma unroll 4
    for (int k = 0; k < 128; ++k) s += Wh1[t * 128 + k] * xr[k];
    z[t] = (s > 0.f) ? s : 0.f;
  }
  __syncthreads();
  if (t < 64) {
    float v = z[t] * Wh2[t];
#pragma unroll
    for (int off = 32; off; off >>= 1) v += __shfl_down(v, off);
    if (t == 0) scores[n] = 1.f / (1.f + __expf(-(v + bh2[0])));
  }
}

// ---------------------------------------------------------------------------

extern "C" void kernel_launch(void* const* d_in, const int* in_sizes, int n_in,
                              void* d_out, int out_size, void* d_ws, size_t ws_size,
                              hipStream_t stream) {
  const float* x   = (const float*)d_in[0];
  const int*   ei  = (const int*)d_in[1];
  const float* W1  = (const float*)d_in[2];
  const float* as1 = (const float*)d_in[3];
  const float* ad1 = (const float*)d_in[4];
  const float* b1  = (const float*)d_in[5];
  const float* W2  = (const float*)d_in[6];
  const float* as2 = (const float*)d_in[7];
  const float* ad2 = (const float*)d_in[8];
  const float* b2  = (const float*)d_in[9];
  const float* W3  = (const float*)d_in[10];
  const float* as3 = (const float*)d_in[11];
  const float* ad3 = (const float*)d_in[12];
  const float* b3  = (const float*)d_in[13];
  const float* Wh1 = (const float*)d_in[14];
  const float* bh1 = (const float*)d_in[15];
  const float* Wh2 = (const float*)d_in[16];
  const float* bh2 = (const float*)d_in[17];
  float* out = (float*)d_out;

  const int F = 256, HC = 512, H = 4, C = 128;
  const int N = in_sizes[0] / F;
  const int E = in_sizes[1] / 2;
  const int Et = E + N;
  const int* srcArr = ei;
  const int* dstArr = ei + E;

  char* ws = (char*)d_ws;
  size_t off = 0;
  auto alloc = [&](size_t bytes) -> void* {
    void* p = ws + off;
    off += (bytes + 255) & ~(size_t)255;
    return p;
  };
  f16*   h16    = (f16*)alloc((size_t)N * HC * 2);     // GEMM out (fp16), 51.2 MB
  f16*   hAgg   = (f16*)alloc((size_t)N * HC * 2);     // aggregate out (fp16), 51.2 MB
  f16*   xh     = (f16*)alloc((size_t)N * F * 2);      // x fp16, 25.6 MB
  f16*   W1h    = (f16*)alloc((size_t)HC * F * 2);
  f16*   W2h    = (f16*)alloc((size_t)HC * HC * 2);
  f16*   W3h    = (f16*)alloc((size_t)C * HC * 2);
  int* row_ptr  = (int*)alloc((size_t)(N + 1) * 4);
  int* cnt      = (int*)alloc((size_t)N * 4);
  int* cursor   = (int*)alloc((size_t)N * 4);
  int* perm     = (int*)alloc((size_t)Et * 4);
  float* sArr   = (float*)alloc((size_t)N * H * 4);
  float* dArr   = (float*)alloc((size_t)N * H * 4);
  (void)ws_size; (void)n_in; (void)out_size;

  // ---- CSR build ----
  hipMemsetAsync(cnt, 0, (size_t)N * 4, stream);
  int eb = (Et + 255) / 256;
  k_count<<<eb, 256, 0, stream>>>(dstArr, cnt, E, Et);
  k_scan<<<1, 1024, 0, stream>>>(cnt, row_ptr, N);
  k_copy<<<(N + 255) / 256, 256, 0, stream>>>(row_ptr, cursor, N);
  k_fill<<<eb, 256, 0, stream>>>(dstArr, cursor, perm, E, Et);

  // ---- fp16 conversions ----
  auto cvt = [&](const float* src, f16* dst, size_t n) {
    int n4 = (int)(n / 4);
    k_f2h<<<(n4 + 255) / 256, 256, 0, stream>>>(src, dst, n4);
  };
  cvt(x, xh, (size_t)N * F);
  cvt(W1, W1h, (size_t)HC * F);
  cvt(W2, W2h, (size_t)HC * HC);
  cvt(W3, W3h, (size_t)C * HC);

  // ---- layer 1: F -> H*C, elu ----
  dim3 g1(HC / 128, (N + 127) / 128);
  k_hgemm_nt<<<g1, 256, 0, stream>>>(xh, W1h, h16, N, HC, F);
  int sdb = (N * H * 64 + 255) / 256;
  k_attn_sd<<<sdb, 256, 0, stream>>>(h16, as1, ad1, sArr, dArr, N, H, C);
  k_aggregate<4, 512, 256, true, f16><<<N, 256, 0, stream>>>(
      h16, sArr, dArr, row_ptr, perm, srcArr, b1, hAgg, N, E);

  // ---- layer 2: H*C -> H*C, elu ----
  k_hgemm_nt<<<g1, 256, 0, stream>>>(hAgg, W2h, h16, N, HC, HC);
  k_attn_sd<<<sdb, 256, 0, stream>>>(h16, as2, ad2, sArr, dArr, N, H, C);
  k_aggregate<4, 512, 256, true, f16><<<N, 256, 0, stream>>>(
      h16, sArr, dArr, row_ptr, perm, srcArr, b2, hAgg, N, E);

  // ---- layer 3: H*C -> C, single head, no concat/elu -> embeddings ----
  dim3 g3(C / 128, (N + 127) / 128);
  k_hgemm_nt<<<g3, 256, 0, stream>>>(hAgg, W3h, h16, N, C, HC);
  int sdb3 = (N * 64 + 255) / 256;
  k_attn_sd<<<sdb3, 256, 0, stream>>>(h16, as3, ad3, sArr, dArr, N, 1, C);
  k_aggregate<1, 128, 64, false, float><<<N, 64, 0, stream>>>(
      h16, sArr, dArr, row_ptr, perm, srcArr, b3, out, N, E);

  // ---- allocation head ----
  k_head<<<N, 128, 0, stream>>>(out, Wh1, bh1, Wh2, bh2, out + (size_t)N * C, N);
}

// Round 4
// 1010.214 us; speedup vs baseline: 1.8121x; 1.1357x over previous
//
#include <hip/hip_runtime.h>
#include <math.h>

typedef _Float16 f16;
typedef f16 f16x2 __attribute__((ext_vector_type(2)));
typedef f16 f16x8 __attribute__((ext_vector_type(8)));
typedef float f32x4 __attribute__((ext_vector_type(4)));

// ---------------------------------------------------------------------------
// CSR build: histogram of dst -> exclusive scan -> fill permutation
// Edge id space: [0, E) = real edges, [E, E+N) = self loops (src=dst=id-E)
// ---------------------------------------------------------------------------

__global__ void k_count(const int* __restrict__ dstArr, int* __restrict__ cnt,
                        int E, int Et) {
  int i = blockIdx.x * blockDim.x + threadIdx.x;
  if (i >= Et) return;
  int d = (i < E) ? dstArr[i] : (i - E);
  atomicAdd(&cnt[d], 1);
}

__global__ __launch_bounds__(1024) void k_scan(const int* __restrict__ cnt,
                                               int* __restrict__ row_ptr, int n) {
  __shared__ int part[1024];
  int t = threadIdx.x;
  int items = (n + 1023) / 1024;
  int base = t * items;
  int local[64];
  int s = 0;
  for (int j = 0; j < items; ++j) {
    int idx = base + j;
    int v = (idx < n) ? cnt[idx] : 0;
    local[j] = s;
    s += v;
  }
  part[t] = s;
  __syncthreads();
  for (int off = 1; off < 1024; off <<= 1) {
    int v = (t >= off) ? part[t - off] : 0;
    __syncthreads();
    part[t] += v;
    __syncthreads();
  }
  int excl = (t == 0) ? 0 : part[t - 1];
  for (int j = 0; j < items; ++j) {
    int idx = base + j;
    if (idx < n) row_ptr[idx] = excl + local[j];
  }
  if (t == 1023) row_ptr[n] = part[1023];
}

__global__ void k_copy(const int* __restrict__ src, int* __restrict__ dst, int n) {
  int i = blockIdx.x * blockDim.x + threadIdx.x;
  if (i < n) dst[i] = src[i];
}

__global__ void k_fill(const int* __restrict__ dstArr, int* __restrict__ cursor,
                       int* __restrict__ perm, int E, int Et) {
  int i = blockIdx.x * blockDim.x + threadIdx.x;
  if (i >= Et) return;
  int d = (i < E) ? dstArr[i] : (i - E);
  int pos = atomicAdd(&cursor[d], 1);
  perm[pos] = i;
}

// ---------------------------------------------------------------------------
// fp32 -> fp16 conversion (vectorized by 4; n must be multiple of 4)
// ---------------------------------------------------------------------------
__global__ void k_f2h(const float* __restrict__ in, f16* __restrict__ out, int n4) {
  int i = blockIdx.x * blockDim.x + threadIdx.x;
  if (i >= n4) return;
  float4 v = ((const float4*)in)[i];
  union { f16 h[4]; double d; } u;
  u.h[0] = (f16)v.x; u.h[1] = (f16)v.y; u.h[2] = (f16)v.z; u.h[3] = (f16)v.w;
  ((double*)out)[i] = u.d;
}

// ---------------------------------------------------------------------------
// HGEMM (fp16 MFMA, fp32 accumulate): C[M,Nn] = A[M,K] @ B[Nn,K]^T
// 128x128 tile, BK=32, 256 thr = 4 waves, wave = 64x64 quadrant (4x4 MFMAs).
// Requires: Nn % 128 == 0, K % 32 == 0. M guarded. fp16 C output.
// ---------------------------------------------------------------------------
#define LDSW 40
__global__ __launch_bounds__(256) void k_hgemm_nt(
    const f16* __restrict__ A, const f16* __restrict__ B,
    f16* __restrict__ C, int M, int Nn, int K) {
  __shared__ f16 As[128 * LDSW];
  __shared__ f16 Bs[128 * LDSW];
  int tid = threadIdx.x;
  int wave = tid >> 6, lane = tid & 63;
  int quad = lane >> 4, l16 = lane & 15;
  int m0 = blockIdx.y * 128, n0 = blockIdx.x * 128;
  int wm = (wave & 1) * 64, wn = (wave >> 1) * 64;

  int srow = tid >> 2;
  int scol = (tid & 3) * 8;
  int ar0 = m0 + srow;       if (ar0 >= M) ar0 = M - 1;
  int ar1 = m0 + srow + 64;  if (ar1 >= M) ar1 = M - 1;
  const f16* Ap0 = A + (size_t)ar0 * K + scol;
  const f16* Ap1 = A + (size_t)ar1 * K + scol;
  const f16* Bp0 = B + (size_t)(n0 + srow) * K + scol;
  const f16* Bp1 = B + (size_t)(n0 + srow + 64) * K + scol;
  f16* Asw0 = &As[srow * LDSW + scol];
  f16* Asw1 = &As[(srow + 64) * LDSW + scol];
  f16* Bsw0 = &Bs[srow * LDSW + scol];
  f16* Bsw1 = &Bs[(srow + 64) * LDSW + scol];

  const f16* Ard[4];
  const f16* Brd[4];
#pragma unroll
  for (int i = 0; i < 4; ++i) {
    Ard[i] = &As[(wm + i * 16 + l16) * LDSW + quad * 8];
    Brd[i] = &Bs[(wn + i * 16 + l16) * LDSW + quad * 8];
  }

  f32x4 acc[4][4];
#pragma unroll
  for (int i = 0; i < 4; ++i)
#pragma unroll
    for (int j = 0; j < 4; ++j) acc[i][j] = (f32x4)(0.f);

  for (int k0 = 0; k0 < K; k0 += 32) {
    f16x8 av0 = *(const f16x8*)(Ap0 + k0);
    f16x8 av1 = *(const f16x8*)(Ap1 + k0);
    f16x8 bv0 = *(const f16x8*)(Bp0 + k0);
    f16x8 bv1 = *(const f16x8*)(Bp1 + k0);
    __syncthreads();
    *(f16x8*)Asw0 = av0;
    *(f16x8*)Asw1 = av1;
    *(f16x8*)Bsw0 = bv0;
    *(f16x8*)Bsw1 = bv1;
    __syncthreads();
    f16x8 af[4], bf[4];
#pragma unroll
    for (int i = 0; i < 4; ++i) af[i] = *(const f16x8*)Ard[i];
#pragma unroll
    for (int j = 0; j < 4; ++j) bf[j] = *(const f16x8*)Brd[j];
#pragma unroll
    for (int i = 0; i < 4; ++i)
#pragma unroll
      for (int j = 0; j < 4; ++j)
        acc[i][j] = __builtin_amdgcn_mfma_f32_16x16x32_f16(af[i], bf[j], acc[i][j], 0, 0, 0);
  }

#pragma unroll
  for (int i = 0; i < 4; ++i) {
#pragma unroll
    for (int r = 0; r < 4; ++r) {
      int m = m0 + wm + i * 16 + quad * 4 + r;
      if (m < M) {
        f16* Cp = C + (size_t)m * Nn + n0 + wn + l16;
#pragma unroll
        for (int j = 0; j < 4; ++j) Cp[j * 16] = (f16)acc[i][j][r];
      }
    }
  }
}

// ---------------------------------------------------------------------------
// Per-node attention scalars from fp16 h: s[n,h] = <h[n,h,:], a_src[h,:]>.
// One wave per (node, head); Cc assumed even.
// ---------------------------------------------------------------------------
__global__ void k_attn_sd(const f16* __restrict__ h,
                          const float* __restrict__ a_src,
                          const float* __restrict__ a_dst,
                          float* __restrict__ sArr, float* __restrict__ dArr,
                          int N, int Hh, int Cc) {
  int gid = blockIdx.x * blockDim.x + threadIdx.x;
  int wid = gid >> 6;
  int lane = gid & 63;
  if (wid >= N * Hh) return;
  int hh = wid % Hh;
  const f16x2* row = (const f16x2*)(h + (size_t)wid * Cc);
  float ss = 0.f, dd = 0.f;
  for (int c2 = lane; c2 < Cc / 2; c2 += 64) {
    f16x2 v = row[c2];
    float v0 = (float)v.x, v1 = (float)v.y;
    ss += v0 * a_src[hh * Cc + 2 * c2] + v1 * a_src[hh * Cc + 2 * c2 + 1];
    dd += v0 * a_dst[hh * Cc + 2 * c2] + v1 * a_dst[hh * Cc + 2 * c2 + 1];
  }
#pragma unroll
  for (int off = 32; off; off >>= 1) {
    ss += __shfl_down(ss, off);
    dd += __shfl_down(dd, off);
  }
  if (lane == 0) { sArr[wid] = ss; dArr[wid] = dd; }
}

// ---------------------------------------------------------------------------
// Per-destination segment softmax + aggregation (CSR, no atomics).
// BLOCK == CT/2; each thread owns one f16x2 of the output row.
// ---------------------------------------------------------------------------
template <int HH, int CT, int BLOCK, bool DOELU, typename OutT>
__global__ __launch_bounds__(BLOCK) void k_aggregate(
    const f16* __restrict__ hin, const float* __restrict__ sArr,
    const float* __restrict__ dArr, const int* __restrict__ row_ptr,
    const int* __restrict__ perm, const int* __restrict__ srcArr,
    const float* __restrict__ bias, OutT* __restrict__ outp, int N, int E) {
  static_assert(BLOCK == CT / 2, "one f16x2 per thread");
  constexpr int CPER2 = (CT / HH) / 2;
  __shared__ float mx_sh[HH];
  __shared__ float denom_sh[HH];
  __shared__ float wbuf[64 * HH];
  __shared__ int sbuf[64];

  int n = blockIdx.x;
  int t = threadIdx.x;
  int e0 = row_ptr[n], e1 = row_ptr[n + 1];
  int deg = e1 - e0;

  float dloc[HH];
#pragma unroll
  for (int h = 0; h < HH; ++h) dloc[h] = dArr[n * HH + h];

  if (t < 64) {
    float mx[HH];
#pragma unroll
    for (int h = 0; h < HH; ++h) mx[h] = -3.0e38f;
    for (int i = t; i < deg; i += 64) {
      int eid = perm[e0 + i];
      int s = (eid < E) ? srcArr[eid] : (eid - E);
#pragma unroll
      for (int h = 0; h < HH; ++h) {
        float e = sArr[s * HH + h] + dloc[h];
        e = (e > 0.f) ? e : 0.2f * e;
        mx[h] = fmaxf(mx[h], e);
      }
    }
#pragma unroll
    for (int h = 0; h < HH; ++h) {
#pragma unroll
      for (int off = 32; off; off >>= 1) mx[h] = fmaxf(mx[h], __shfl_down(mx[h], off));
    }
    if (t == 0) {
#pragma unroll
      for (int h = 0; h < HH; ++h) { mx_sh[h] = mx[h]; denom_sh[h] = 0.f; }
    }
  }
  __syncthreads();

  int hh = t / CPER2;
  float acc0 = 0.f, acc1 = 0.f;

  for (int base = 0; base < deg; base += 64) {
    int cn = min(64, deg - base);
    if (t < cn) {
      int eid = perm[e0 + base + t];
      int s = (eid < E) ? srcArr[eid] : (eid - E);
      sbuf[t] = s;
#pragma unroll
      for (int h = 0; h < HH; ++h) {
        float e = sArr[s * HH + h] + dloc[h];
        e = (e > 0.f) ? e : 0.2f * e;
        wbuf[t * HH + h] = __expf(e - mx_sh[h]);
      }
    }
    __syncthreads();
    if (t < HH) {
      float dsum = 0.f;
      for (int i = 0; i < cn; ++i) dsum += wbuf[i * HH + t];
      denom_sh[t] += dsum;
    }
    for (int i = 0; i < cn; ++i) {
      int s = sbuf[i];
      f16x2 v = ((const f16x2*)(hin + (size_t)s * CT))[t];
      float w = wbuf[i * HH + hh];
      acc0 += w * (float)v.x;
      acc1 += w * (float)v.y;
    }
    __syncthreads();
  }

  float dn = denom_sh[hh] + 1e-16f;
  float v0 = acc0 / dn + bias[2 * t];
  float v1 = acc1 / dn + bias[2 * t + 1];
  if (DOELU) {
    v0 = (v0 > 0.f) ? v0 : expm1f(v0);
    v1 = (v1 > 0.f) ? v1 : expm1f(v1);
  }
  if constexpr (sizeof(OutT) == 2) {
    f16x2 o; o.x = (f16)v0; o.y = (f16)v1;
    ((f16x2*)(outp + (size_t)n * CT))[t] = o;
  } else {
    float2 o = make_float2(v0, v1);
    ((float2*)(outp + (size_t)n * CT))[t] = o;
  }
}

// ---------------------------------------------------------------------------
// Allocation head: z = relu(emb @ Wh1^T + bh1); score = sigmoid(z @ Wh2^T + bh2)
// Persistent blocks; Wh1 staged in LDS once per block (stride 132 breaks the
// stride-128 b128 bank aliasing). One wave per node iteration: lane l owns
// z[l]; x-row broadcast via shuffles; width-64 shuffle reduce for layer 2.
// ---------------------------------------------------------------------------
__global__ __launch_bounds__(256) void k_head(
    const float* __restrict__ emb, const float* __restrict__ Wh1,
    const float* __restrict__ bh1, const float* __restrict__ Wh2,
    const float* __restrict__ bh2, float* __restrict__ scores, int N) {
  __shared__ float w1s[64 * 132];
  __shared__ float w2s[64];
  __shared__ float b1s[64];
  int t = threadIdx.x;
  for (int i = t; i < 64 * 32; i += 256) {  // i indexes float4 units
    int r = i >> 5, c4 = i & 31;
    float4 v = ((const float4*)Wh1)[i];
    *(float4*)&w1s[r * 132 + c4 * 4] = v;
  }
  if (t < 64) { w2s[t] = Wh2[t]; b1s[t] = bh1[t]; }
  __syncthreads();
  float b2v = bh2[0];
  int wave = t >> 6, lane = t & 63;
  int gw = blockIdx.x * 4 + wave;
  int nw = gridDim.x * 4;
  for (int n = gw; n < N; n += nw) {
    float2 xv = ((const float2*)(emb + (size_t)n * 128))[lane];  // x[2l],x[2l+1]
    float z = b1s[lane];
#pragma unroll
    for (int j = 0; j < 32; ++j) {
      float4 w = *(const float4*)&w1s[lane * 132 + 4 * j];
      float a0 = __shfl(xv.x, 2 * j);
      float a1 = __shfl(xv.y, 2 * j);
      float a2 = __shfl(xv.x, 2 * j + 1);
      float a3 = __shfl(xv.y, 2 * j + 1);
      z += w.x * a0 + w.y * a1 + w.z * a2 + w.w * a3;
    }
    z = fmaxf(z, 0.f);
    float v = z * w2s[lane];
#pragma unroll
    for (int off = 32; off; off >>= 1) v += __shfl_down(v, off);
    if (lane == 0) scores[n] = 1.f / (1.f + __expf(-(v + b2v)));
  }
}

// ---------------------------------------------------------------------------

extern "C" void kernel_launch(void* const* d_in, const int* in_sizes, int n_in,
                              void* d_out, int out_size, void* d_ws, size_t ws_size,
                              hipStream_t stream) {
  const float* x   = (const float*)d_in[0];
  const int*   ei  = (const int*)d_in[1];
  const float* W1  = (const float*)d_in[2];
  const float* as1 = (const float*)d_in[3];
  const float* ad1 = (const float*)d_in[4];
  const float* b1  = (const float*)d_in[5];
  const float* W2  = (const float*)d_in[6];
  const float* as2 = (const float*)d_in[7];
  const float* ad2 = (const float*)d_in[8];
  const float* b2  = (const float*)d_in[9];
  const float* W3  = (const float*)d_in[10];
  const float* as3 = (const float*)d_in[11];
  const float* ad3 = (const float*)d_in[12];
  const float* b3  = (const float*)d_in[13];
  const float* Wh1 = (const float*)d_in[14];
  const float* bh1 = (const float*)d_in[15];
  const float* Wh2 = (const float*)d_in[16];
  const float* bh2 = (const float*)d_in[17];
  float* out = (float*)d_out;

  const int F = 256, HC = 512, H = 4, C = 128;
  const int N = in_sizes[0] / F;
  const int E = in_sizes[1] / 2;
  const int Et = E + N;
  const int* srcArr = ei;
  const int* dstArr = ei + E;

  char* ws = (char*)d_ws;
  size_t off = 0;
  auto alloc = [&](size_t bytes) -> void* {
    void* p = ws + off;
    off += (bytes + 255) & ~(size_t)255;
    return p;
  };
  f16*   h16    = (f16*)alloc((size_t)N * HC * 2);
  f16*   hAgg   = (f16*)alloc((size_t)N * HC * 2);
  f16*   xh     = (f16*)alloc((size_t)N * F * 2);
  f16*   W1h    = (f16*)alloc((size_t)HC * F * 2);
  f16*   W2h    = (f16*)alloc((size_t)HC * HC * 2);
  f16*   W3h    = (f16*)alloc((size_t)C * HC * 2);
  int* row_ptr  = (int*)alloc((size_t)(N + 1) * 4);
  int* cnt      = (int*)alloc((size_t)N * 4);
  int* cursor   = (int*)alloc((size_t)N * 4);
  int* perm     = (int*)alloc((size_t)Et * 4);
  float* sArr   = (float*)alloc((size_t)N * H * 4);
  float* dArr   = (float*)alloc((size_t)N * H * 4);
  (void)ws_size; (void)n_in; (void)out_size;

  // ---- CSR build ----
  hipMemsetAsync(cnt, 0, (size_t)N * 4, stream);
  int eb = (Et + 255) / 256;
  k_count<<<eb, 256, 0, stream>>>(dstArr, cnt, E, Et);
  k_scan<<<1, 1024, 0, stream>>>(cnt, row_ptr, N);
  k_copy<<<(N + 255) / 256, 256, 0, stream>>>(row_ptr, cursor, N);
  k_fill<<<eb, 256, 0, stream>>>(dstArr, cursor, perm, E, Et);

  // ---- fp16 conversions ----
  auto cvt = [&](const float* src, f16* dst, size_t n) {
    int n4 = (int)(n / 4);
    k_f2h<<<(n4 + 255) / 256, 256, 0, stream>>>(src, dst, n4);
  };
  cvt(x, xh, (size_t)N * F);
  cvt(W1, W1h, (size_t)HC * F);
  cvt(W2, W2h, (size_t)HC * HC);
  cvt(W3, W3h, (size_t)C * HC);

  // ---- layer 1: F -> H*C, elu ----
  dim3 g1(HC / 128, (N + 127) / 128);
  k_hgemm_nt<<<g1, 256, 0, stream>>>(xh, W1h, h16, N, HC, F);
  int sdb = (N * H * 64 + 255) / 256;
  k_attn_sd<<<sdb, 256, 0, stream>>>(h16, as1, ad1, sArr, dArr, N, H, C);
  k_aggregate<4, 512, 256, true, f16><<<N, 256, 0, stream>>>(
      h16, sArr, dArr, row_ptr, perm, srcArr, b1, hAgg, N, E);

  // ---- layer 2: H*C -> H*C, elu ----
  k_hgemm_nt<<<g1, 256, 0, stream>>>(hAgg, W2h, h16, N, HC, HC);
  k_attn_sd<<<sdb, 256, 0, stream>>>(h16, as2, ad2, sArr, dArr, N, H, C);
  k_aggregate<4, 512, 256, true, f16><<<N, 256, 0, stream>>>(
      h16, sArr, dArr, row_ptr, perm, srcArr, b2, hAgg, N, E);

  // ---- layer 3: H*C -> C, single head, no concat/elu -> embeddings ----
  dim3 g3(C / 128, (N + 127) / 128);
  k_hgemm_nt<<<g3, 256, 0, stream>>>(hAgg, W3h, h16, N, C, HC);
  int sdb3 = (N * 64 + 255) / 256;
  k_attn_sd<<<sdb3, 256, 0, stream>>>(h16, as3, ad3, sArr, dArr, N, 1, C);
  k_aggregate<1, 128, 64, false, float><<<N, 64, 0, stream>>>(
      h16, sArr, dArr, row_ptr, perm, srcArr, b3, out, N, E);

  // ---- allocation head ----
  k_head<<<512, 256, 0, stream>>>(out, Wh1, bh1, Wh2, bh2, out + (size_t)N * C, N);
}